// Round 1
// 67.299 us; speedup vs baseline: 1.0048x; 1.0048x over previous
//
#include <hip/hip_runtime.h>
#include <hip/hip_bf16.h>

// HGT_DNF folded (idx=[0..52,0..52] => W[n]=weights[n%53]).
// out[b,o] = MFMA-GEMM K=192: seg1 A=xm,B=w; seg2 A=-d*s,B=|w|;
//            seg3 A=(m/4.5)^8, B=(2|w|)^8 -> ac2; term = d*2.25*ac2^(1/8).
// R14 = R13 with the grid restructured to cut redundant A-stage VALU work:
//  - R13: dim3(8,128) x 256 thr; every 32-row group's x-transform was
//    recomputed by all 8 col-group blocks (A-stage = 4 iters/wave).
//  - R14: dim3(2,128) x 1024 thr (16 waves); block = 32 rows x 512 cols.
//    A-transform redundancy x8 -> x2; A-stage = 1 iter/wave (2 rows).
//    ~25% fewer issued instructions/lane at identical occupancy
//    (16 waves/CU = 4 waves/SIMD, 12.8 KB LDS, 128-VGPR cap) and
//    identical GEMM/epilogue code.

typedef _Float16 v8h __attribute__((ext_vector_type(8)));
typedef float v4f __attribute__((ext_vector_type(4)));
typedef _Float16 h2 __attribute__((ext_vector_type(2)));
typedef unsigned int u32;

#define N_PRED 106
#define OUT_N 1024
#define DELTA_C 0.01f
#define RMG 0.22222222f   // 1/4.5
#define SROW 100          // u32 per A-row: 96 + 4 pad

static __device__ __forceinline__ u32 pk2u(float a, float b) {
    return __builtin_bit_cast(u32, __builtin_amdgcn_cvt_pkrtz(a, b));
}
static __device__ __forceinline__ u32 pow8_pk(u32 qa) {
    h2 v = __builtin_bit_cast(h2, qa);
    v = v + v;          // 2|w|
    v = v * v; v = v * v; v = v * v;   // ^8
    return __builtin_bit_cast(u32, v);
}

__global__ __launch_bounds__(1024, 4) void fused_kernel(
    const float* __restrict__ x,    // [4096][106]
    const float* __restrict__ w,    // [54][1024]
    float* __restrict__ out) {      // [4096][1024]
    __shared__ __attribute__((aligned(16))) u32 AL[32 * SROW];  // 12.8 KB

    const int t = threadIdx.x;
    const int cg = blockIdx.x;   // 0..1   : 512-col group
    const int mg = blockIdx.y;   // 0..127 : 32-row group
    const int lane = t & 63;
    const int wv = __builtin_amdgcn_readfirstlane(t >> 6);  // 0..15
    const int l16 = lane & 15, quad = lane >> 4;
    const int cbase = cg * 512 + wv * 32;

    // ---- B frags: w / |w| from global ----
    v8h bfw[2][2], bfa[2][2];
#pragma unroll
    for (int nt = 0; nt < 2; ++nt)
#pragma unroll
        for (int kcb = 0; kcb < 2; ++kcb) {
            float f[8];
#pragma unroll
            for (int jj = 0; jj < 8; ++jj) {
                int k = kcb * 32 + quad * 8 + jj;
                int row = k < 54 ? k : 53;   // A=0 there; value moot
                f[jj] = w[row * OUT_N + cbase + nt * 16 + l16];
            }
            uint4 q = make_uint4(pk2u(f[0], f[1]), pk2u(f[2], f[3]),
                                 pk2u(f[4], f[5]), pk2u(f[6], f[7]));
            bfw[nt][kcb] = __builtin_bit_cast(v8h, q);
            uint4 qa = make_uint4(q.x & 0x7FFF7FFFu, q.y & 0x7FFF7FFFu,
                                  q.z & 0x7FFF7FFFu, q.w & 0x7FFF7FFFu);
            bfa[nt][kcb] = __builtin_bit_cast(v8h, qa);
        }

    // ---- A stage: each wave stages 2 rows, one shot; j-pairs packed ----
    const int half = lane >> 5;   // 0: even row, 1: odd row
    const int jp = lane & 31;     // j-pair index; valid pairs 0..26
    const bool v0 = jp <= 26, v1 = jp <= 25;
    const int rl = wv * 2 + half;                  // row in block's 32
    const float* xr = x + ((size_t)mg * 32 + rl) * N_PRED;
    {
        float lo0 = 0.f, lo1 = 0.f, hi0 = 0.f, hi1 = 0.f;
        if (v0) {
            float2 lo = *(const float2*)(xr + 2 * jp);  // 8B-aligned
            lo0 = lo.x; lo1 = lo.y;
            hi0 = xr[53 + 2 * jp];
            if (v1) hi1 = xr[54 + 2 * jp];
        }
        float a0 = fabsf(lo0), b0 = fabsf(hi0);
        float a1 = fabsf(lo1), b1 = fabsf(hi1);
        float xm0 = v0 ? ((lo0 >= -1.f ? lo0 : 0.f) + (hi0 >= -1.f ? hi0 : 0.f)) : 0.f;
        float xm1 = v1 ? ((lo1 >= -1.f ? lo1 : 0.f) + (hi1 >= -1.f ? hi1 : 0.f)) : 0.f;
        float sn0 = v0 ? -DELTA_C * (a0 + b0) : 0.f;
        float sn1 = v1 ? -DELTA_C * (a1 + b1) : 0.f;
        float m0 = fmaxf(a0, b0) * RMG, m1 = fmaxf(a1, b1) * RMG;
        m0 = m0 * m0; m0 = m0 * m0; m0 = m0 * m0;   // (m/4.5)^8
        m1 = m1 * m1; m1 = m1 * m1; m1 = m1 * m1;
        if (!v0) m0 = 0.f;
        if (!v1) m1 = 0.f;
        u32* Ar = &AL[rl * SROW];
        Ar[jp] = pk2u(xm0, xm1);        // seg1: k-pairs 0..31
        Ar[32 + jp] = pk2u(sn0, sn1);   // seg2
        Ar[64 + jp] = pk2u(m0, m1);     // seg3
    }
    __syncthreads();

    // ---- GEMM phase 1: seg1+seg2 (16 MFMA), only bfw/bfa resident ----
    v4f acc[2][2], ac2[2][2];
#pragma unroll
    for (int mt = 0; mt < 2; ++mt)
#pragma unroll
        for (int nt = 0; nt < 2; ++nt) { acc[mt][nt] = (v4f)0.f; ac2[mt][nt] = (v4f)0.f; }

#pragma unroll
    for (int mt = 0; mt < 2; ++mt) {
        v8h af[4];
#pragma unroll
        for (int kc = 0; kc < 4; ++kc)
            af[kc] = *(const v8h*)&AL[(mt * 16 + l16) * SROW + kc * 16 + quad * 4];
#pragma unroll
        for (int nt = 0; nt < 2; ++nt) {
            acc[mt][nt] = __builtin_amdgcn_mfma_f32_16x16x32_f16(af[0], bfw[nt][0], acc[mt][nt], 0, 0, 0);
            acc[mt][nt] = __builtin_amdgcn_mfma_f32_16x16x32_f16(af[1], bfw[nt][1], acc[mt][nt], 0, 0, 0);
            acc[mt][nt] = __builtin_amdgcn_mfma_f32_16x16x32_f16(af[2], bfa[nt][0], acc[mt][nt], 0, 0, 0);
            acc[mt][nt] = __builtin_amdgcn_mfma_f32_16x16x32_f16(af[3], bfa[nt][1], acc[mt][nt], 0, 0, 0);
        }
    }

    // ---- transform bfa -> (2|w|)^8 in place (bfa dead after seg2) ----
#pragma unroll
    for (int nt = 0; nt < 2; ++nt)
#pragma unroll
        for (int kcb = 0; kcb < 2; ++kcb) {
            uint4 qa = __builtin_bit_cast(uint4, bfa[nt][kcb]);
            qa = make_uint4(pow8_pk(qa.x), pow8_pk(qa.y),
                            pow8_pk(qa.z), pow8_pk(qa.w));
            bfa[nt][kcb] = __builtin_bit_cast(v8h, qa);
        }

    // ---- GEMM phase 2: seg3 (8 MFMA) ----
#pragma unroll
    for (int mt = 0; mt < 2; ++mt) {
        v8h ag[2];
        ag[0] = *(const v8h*)&AL[(mt * 16 + l16) * SROW + 64 + quad * 4];
        ag[1] = *(const v8h*)&AL[(mt * 16 + l16) * SROW + 80 + quad * 4];
#pragma unroll
        for (int nt = 0; nt < 2; ++nt) {
            ac2[mt][nt] = __builtin_amdgcn_mfma_f32_16x16x32_f16(ag[0], bfa[nt][0], ac2[mt][nt], 0, 0, 0);
            ac2[mt][nt] = __builtin_amdgcn_mfma_f32_16x16x32_f16(ag[1], bfa[nt][1], ac2[mt][nt], 0, 0, 0);
        }
    }

    // ---- epilogue: out = acc + d*4.5*0.5 * ac2^(1/8);  s^(1/8)=sqrt^3 ----
#pragma unroll
    for (int mt = 0; mt < 2; ++mt)
#pragma unroll
        for (int nt = 0; nt < 2; ++nt)
#pragma unroll
            for (int r = 0; r < 4; ++r) {
                float s = ac2[mt][nt][r];
                float root = __builtin_amdgcn_sqrtf(
                    __builtin_amdgcn_sqrtf(__builtin_amdgcn_sqrtf(s)));
                out[(size_t)(mg * 32 + mt * 16 + quad * 4 + r) * OUT_N +
                    cbase + nt * 16 + l16] = acc[mt][nt][r] + 0.0225f * root;
            }
}

extern "C" void kernel_launch(void* const* d_in, const int* in_sizes, int n_in,
                              void* d_out, int out_size, void* d_ws, size_t ws_size,
                              hipStream_t stream) {
    const float* x = (const float*)d_in[0];        // [4096,106]
    const float* weights = (const float*)d_in[1];  // [54,1024]
    float* out = (float*)d_out;                    // [4096,1024]
    (void)d_ws; (void)ws_size;

    fused_kernel<<<dim3(2, 128), dim3(1024), 0, stream>>>(x, weights, out);
}